// Round 3
// baseline (664.042 us; speedup 1.0000x reference)
//
#include <hip/hip_runtime.h>

#define NTOK 2048
#define NEXP 8
#define TOPK 2
#define NITEM 4096   // NTOK*TOPK
#define DIM 1024
#define HID 2816
#define CAP 4096
#define LDP 72       // padded LDS row stride in u16 (144B, 16B-aligned, non-pow2)

typedef unsigned short u16;
typedef __bf16 bf16x8 __attribute__((ext_vector_type(8)));
typedef float f32x4 __attribute__((ext_vector_type(4)));

__device__ __forceinline__ u16 f2bf(float f) {
  unsigned u = __float_as_uint(f);
  return (u16)((u + 0x7FFFu + ((u >> 16) & 1u)) >> 16);
}
__device__ __forceinline__ unsigned pk2(float a, float b) {
  return (unsigned)f2bf(a) | ((unsigned)f2bf(b) << 16);
}

__global__ void zero8(int* counts) {
  if (threadIdx.x < NEXP) counts[threadIdx.x] = 0;
}

__global__ void bucket(const int* __restrict__ ei, int* counts, int* lists) {
  int item = blockIdx.x * 256 + threadIdx.x;
  if (item < NITEM) {
    int e = ei[item];
    e &= 7;  // sanitize
    int pos = atomicAdd(&counts[e], 1);
    if (pos < CAP) lists[e * CAP + pos] = item;
  }
}

// GEMM1: for expert e, X_e[128 items x DIM] * {w1,w3}[e]^T [128 h x DIM] -> G = silu(x1)*x3 (bf16)
// NOTE: item i corresponds to token row (i >> 1) of x; G/out rows are indexed by item.
__global__ __launch_bounds__(256, 2) void gemm1(
    const float* __restrict__ x, const float* __restrict__ w1,
    const float* __restrict__ w3, const int* __restrict__ counts,
    const int* __restrict__ lists, u16* __restrict__ G) {
  __shared__ __align__(16) u16 As[128 * LDP];
  __shared__ __align__(16) u16 B1s[128 * LDP];
  __shared__ __align__(16) u16 B3s[128 * LDP];
  __shared__ int toks[128];

  const int e = blockIdx.z;
  int cnt = counts[e];
  if ((unsigned)cnt > CAP) cnt = 0;
  const int m0 = blockIdx.y * 128;
  if (m0 >= cnt) return;
  const int n0 = blockIdx.x * 128;
  const int tid = threadIdx.x;

  if (tid < 128) {
    int r = m0 + tid;
    int it = lists[e * CAP + (r < cnt ? r : 0)];
    toks[tid] = ((unsigned)it < NITEM) ? it : 0;
  }
  __syncthreads();

  const int lane = tid & 63;
  const int wr = ((tid >> 7) & 1) * 64;   // wave row offset (2x2 wave grid)
  const int wc = ((tid >> 6) & 1) * 64;   // wave col offset
  const int lr = lane & 15;
  const int kg = lane >> 4;

  const int arow = tid >> 3;        // 0..31
  const int c8 = (tid & 7) * 8;     // 0..56, 8-elem chunk

  const float* xsrc[4];
#pragma unroll
  for (int p = 0; p < 4; ++p)
    xsrc[p] = x + (size_t)(toks[p * 32 + arow] >> 1) * DIM + c8;  // item -> token row

  const float* w1p = w1 + ((size_t)e * HID + n0 + arow) * DIM + c8;
  const float* w3p = w3 + ((size_t)e * HID + n0 + arow) * DIM + c8;

  f32x4 acc1[4][4] = {};
  f32x4 acc3[4][4] = {};

  for (int k0 = 0; k0 < DIM; k0 += 64) {
    // stage A (gathered token rows of x, f32 -> bf16)
#pragma unroll
    for (int p = 0; p < 4; ++p) {
      float4 v0 = *(const float4*)(xsrc[p] + k0);
      float4 v1 = *(const float4*)(xsrc[p] + k0 + 4);
      uint4 u;
      u.x = pk2(v0.x, v0.y); u.y = pk2(v0.z, v0.w);
      u.z = pk2(v1.x, v1.y); u.w = pk2(v1.z, v1.w);
      *(uint4*)&As[(p * 32 + arow) * LDP + c8] = u;
    }
    // stage B1/B3 (weight rows, f32 -> bf16)
#pragma unroll
    for (int p = 0; p < 4; ++p) {
      float4 v0 = *(const float4*)(w1p + (size_t)(p * 32) * DIM + k0);
      float4 v1 = *(const float4*)(w1p + (size_t)(p * 32) * DIM + k0 + 4);
      uint4 u;
      u.x = pk2(v0.x, v0.y); u.y = pk2(v0.z, v0.w);
      u.z = pk2(v1.x, v1.y); u.w = pk2(v1.z, v1.w);
      *(uint4*)&B1s[(p * 32 + arow) * LDP + c8] = u;
      v0 = *(const float4*)(w3p + (size_t)(p * 32) * DIM + k0);
      v1 = *(const float4*)(w3p + (size_t)(p * 32) * DIM + k0 + 4);
      u.x = pk2(v0.x, v0.y); u.y = pk2(v0.z, v0.w);
      u.z = pk2(v1.x, v1.y); u.w = pk2(v1.z, v1.w);
      *(uint4*)&B3s[(p * 32 + arow) * LDP + c8] = u;
    }
    __syncthreads();
#pragma unroll
    for (int kk = 0; kk < 2; ++kk) {
      const int ko = kk * 32 + kg * 8;
      bf16x8 a[4];
#pragma unroll
      for (int m = 0; m < 4; ++m)
        a[m] = *(const bf16x8*)&As[(wr + m * 16 + lr) * LDP + ko];
#pragma unroll
      for (int n = 0; n < 4; ++n) {
        bf16x8 b1 = *(const bf16x8*)&B1s[(wc + n * 16 + lr) * LDP + ko];
        bf16x8 b3 = *(const bf16x8*)&B3s[(wc + n * 16 + lr) * LDP + ko];
#pragma unroll
        for (int m = 0; m < 4; ++m) {
          acc1[m][n] = __builtin_amdgcn_mfma_f32_16x16x32_bf16(a[m], b1, acc1[m][n], 0, 0, 0);
          acc3[m][n] = __builtin_amdgcn_mfma_f32_16x16x32_bf16(a[m], b3, acc3[m][n], 0, 0, 0);
        }
      }
    }
    __syncthreads();
  }

#pragma unroll
  for (int m = 0; m < 4; ++m) {
#pragma unroll
    for (int r = 0; r < 4; ++r) {
      const int row = wr + m * 16 + kg * 4 + r;
      if (m0 + row < cnt) {
        const int it = toks[row];
        u16* gp = G + (size_t)it * HID + n0 + wc + lr;
#pragma unroll
        for (int n = 0; n < 4; ++n) {
          float v1 = acc1[m][n][r];
          float v3 = acc3[m][n][r];
          float s = v1 / (1.f + __expf(-v1)) * v3;
          gp[n * 16] = f2bf(s);
        }
      }
    }
  }
}

// GEMM2: out[item][d] = G[item][:] . w2[e][:][d]  (w2 transposed on the fly in LDS)
__global__ __launch_bounds__(256, 2) void gemm2(
    const u16* __restrict__ G, const float* __restrict__ w2,
    const int* __restrict__ counts, const int* __restrict__ lists,
    float* __restrict__ out) {
  __shared__ __align__(16) u16 As[128 * LDP];
  __shared__ __align__(16) u16 Bs[128 * LDP];   // Bs[d_local][h_local]
  __shared__ int toks[128];

  const int e = blockIdx.z;
  int cnt = counts[e];
  if ((unsigned)cnt > CAP) cnt = 0;
  const int m0 = blockIdx.y * 128;
  if (m0 >= cnt) return;
  const int n0 = blockIdx.x * 128;
  const int tid = threadIdx.x;

  if (tid < 128) {
    int r = m0 + tid;
    int it = lists[e * CAP + (r < cnt ? r : 0)];
    toks[tid] = ((unsigned)it < NITEM) ? it : 0;
  }
  __syncthreads();

  const int lane = tid & 63;
  const int wr = ((tid >> 7) & 1) * 64;
  const int wc = ((tid >> 6) & 1) * 64;
  const int lr = lane & 15;
  const int kg = lane >> 4;

  const int arow = tid >> 3;
  const int c8 = (tid & 7) * 8;
  const int brow = tid >> 5;       // 0..7  (h sub-row)
  const int d4 = (tid & 31) * 4;   // 0..124

  const u16* asrc[4];
#pragma unroll
  for (int p = 0; p < 4; ++p)
    asrc[p] = G + (size_t)toks[p * 32 + arow] * HID + c8;
  const float* bsrc = w2 + ((size_t)e * HID) * DIM + n0 + d4;

  f32x4 acc[4][4] = {};

  for (int k0 = 0; k0 < HID; k0 += 64) {
    // stage A: gathered G rows (already bf16) — straight 16B copies
#pragma unroll
    for (int p = 0; p < 4; ++p) {
      uint4 u = *(const uint4*)(asrc[p] + k0);
      *(uint4*)&As[(p * 32 + arow) * LDP + c8] = u;
    }
    // stage B with transpose: Bs[d][h] = bf16(w2[e][k0+h][n0+d])
#pragma unroll
    for (int p = 0; p < 8; ++p) {
      const int hl = p * 8 + brow;  // 0..63
      float4 v = *(const float4*)(bsrc + (size_t)(k0 + hl) * DIM);
      Bs[(d4 + 0) * LDP + hl] = f2bf(v.x);
      Bs[(d4 + 1) * LDP + hl] = f2bf(v.y);
      Bs[(d4 + 2) * LDP + hl] = f2bf(v.z);
      Bs[(d4 + 3) * LDP + hl] = f2bf(v.w);
    }
    __syncthreads();
#pragma unroll
    for (int kk = 0; kk < 2; ++kk) {
      const int ko = kk * 32 + kg * 8;
      bf16x8 a[4];
#pragma unroll
      for (int m = 0; m < 4; ++m)
        a[m] = *(const bf16x8*)&As[(wr + m * 16 + lr) * LDP + ko];
#pragma unroll
      for (int n = 0; n < 4; ++n) {
        bf16x8 b = *(const bf16x8*)&Bs[(wc + n * 16 + lr) * LDP + ko];
#pragma unroll
        for (int m = 0; m < 4; ++m)
          acc[m][n] = __builtin_amdgcn_mfma_f32_16x16x32_bf16(a[m], b, acc[m][n], 0, 0, 0);
      }
    }
    __syncthreads();
  }

#pragma unroll
  for (int m = 0; m < 4; ++m) {
#pragma unroll
    for (int r = 0; r < 4; ++r) {
      const int row = wr + m * 16 + kg * 4 + r;
      if (m0 + row < cnt) {
        const int it = toks[row];
        float* op = out + (size_t)it * DIM + n0 + wc + lr;
#pragma unroll
        for (int n = 0; n < 4; ++n)
          op[n * 16] = acc[m][n][r];
      }
    }
  }
}

extern "C" void kernel_launch(void* const* d_in, const int* in_sizes, int n_in,
                              void* d_out, int out_size, void* d_ws, size_t ws_size,
                              hipStream_t stream) {
  (void)in_sizes; (void)n_in; (void)out_size; (void)ws_size;
  const float* x  = (const float*)d_in[0];
  const int*   ei = (const int*)d_in[1];
  const float* w1 = (const float*)d_in[2];
  const float* w2 = (const float*)d_in[3];
  const float* w3 = (const float*)d_in[4];
  float* out = (float*)d_out;

  // compact workspace: G (23,068,672 B) | counts (64 B) | lists (131,072 B)
  char* ws = (char*)d_ws;
  u16* G      = (u16*)ws;
  int* counts = (int*)(ws + 23068672u);
  int* lists  = (int*)(ws + 23068736u);

  zero8<<<1, 64, 0, stream>>>(counts);
  bucket<<<NITEM / 256, 256, 0, stream>>>(ei, counts, lists);
  gemm1<<<dim3(HID / 128, CAP / 128, NEXP), 256, 0, stream>>>(x, w1, w3, counts, lists, G);
  gemm2<<<dim3(DIM / 128, CAP / 128, NEXP), 256, 0, stream>>>(G, w2, counts, lists, out);
}

// Round 4
// 240.639 us; speedup vs baseline: 2.7595x; 2.7595x over previous
//
#include <hip/hip_runtime.h>

#define NTOK 2048
#define NEXP 8
#define TOPK 2
#define NITEM 4096   // NTOK*TOPK
#define DIM 1024
#define HID 2816
#define CAP 4096
#define LDP 72       // fallback-path padded LDS stride (u16)

typedef unsigned short u16;
typedef __bf16 bf16x8 __attribute__((ext_vector_type(8)));
typedef float f32x4 __attribute__((ext_vector_type(4)));

__device__ __forceinline__ u16 f2bf(float f) {
  unsigned u = __float_as_uint(f);
  return (u16)((u + 0x7FFFu + ((u >> 16) & 1u)) >> 16);
}
__device__ __forceinline__ unsigned pk2(float a, float b) {
  return (unsigned)f2bf(a) | ((unsigned)f2bf(b) << 16);
}
__device__ __forceinline__ void async16(const void* g, void* l) {
  __builtin_amdgcn_global_load_lds(
      (const __attribute__((address_space(1))) unsigned int*)g,
      (__attribute__((address_space(3))) unsigned int*)l, 16, 0, 0);
}
// XOR-swizzled fragment pointer into a [rows][64] u16 LDS tile (linear dest layout,
// source columns pre-swizzled at global_load_lds time; see staging code).
__device__ __forceinline__ const bf16x8* fragp(const u16* base, int row, int ko) {
  int byte = ((row << 7) + (ko << 1)) ^ ((row & 7) << 4);
  return (const bf16x8*)((const char*)base + byte);
}

__global__ void zero8(int* counts) {
  if (threadIdx.x < NEXP) counts[threadIdx.x] = 0;
}

__global__ void bucket(const int* __restrict__ ei, int* counts, int* lists) {
  int item = blockIdx.x * 256 + threadIdx.x;
  if (item < NITEM) {
    int e = ei[item] & 7;
    int pos = atomicAdd(&counts[e], 1);
    if (pos < CAP) lists[e * CAP + pos] = item;
  }
}

// generic f32 -> bf16 convert, 8 elems/thread
__global__ __launch_bounds__(256) void cvt8(const float* __restrict__ src,
                                            u16* __restrict__ dst, int n8) {
  int i = blockIdx.x * 256 + threadIdx.x;
  if (i >= n8) return;
  float4 v0 = *(const float4*)(src + (size_t)i * 8);
  float4 v1 = *(const float4*)(src + (size_t)i * 8 + 4);
  uint4 u;
  u.x = pk2(v0.x, v0.y); u.y = pk2(v0.z, v0.w);
  u.z = pk2(v1.x, v1.y); u.w = pk2(v1.z, v1.w);
  *(uint4*)(dst + (size_t)i * 8) = u;
}

// w2 [E][H][D] f32 -> w2t [E][D][H] bf16, 64x64 LDS tile transpose
__global__ __launch_bounds__(256) void tw2(const float* __restrict__ w2, u16* __restrict__ w2t) {
  __shared__ float tile[64][65];
  const int e = blockIdx.z;
  const int h0 = blockIdx.y * 64;
  const int d0 = blockIdx.x * 64;
  const int tid = threadIdx.x;
  const int r = tid >> 4, c = (tid & 15) * 4;
  const float* src = w2 + (size_t)e * HID * DIM;
#pragma unroll
  for (int p = 0; p < 4; ++p) {
    float4 v = *(const float4*)(src + (size_t)(h0 + p * 16 + r) * DIM + d0 + c);
    tile[p * 16 + r][c] = v.x;
    tile[p * 16 + r][c + 1] = v.y;
    tile[p * 16 + r][c + 2] = v.z;
    tile[p * 16 + r][c + 3] = v.w;
  }
  __syncthreads();
  u16* dst = w2t + (size_t)e * DIM * HID;
#pragma unroll
  for (int p = 0; p < 4; ++p) {
    int dd = p * 16 + r;
    uint2 pkv;
    pkv.x = pk2(tile[c][dd], tile[c + 1][dd]);
    pkv.y = pk2(tile[c + 2][dd], tile[c + 3][dd]);
    *(uint2*)(dst + (size_t)(d0 + dd) * HID + h0 + c) = pkv;
  }
}

// ---------------- Path A: all-bf16 GEMMs with global_load_lds + swizzle ----------------

// GEMM1: X_e[128 items x DIM] * {w1b,w3b}[e]^T[128 h x DIM] -> G = silu(x1)*x3 (bf16)
__global__ __launch_bounds__(256, 2) void gemm1A(
    const u16* __restrict__ xb, const u16* __restrict__ w1b,
    const u16* __restrict__ w3b, const int* __restrict__ counts,
    const int* __restrict__ lists, u16* __restrict__ G) {
  __shared__ __align__(16) u16 As[128 * 64];
  __shared__ __align__(16) u16 B1s[128 * 64];
  __shared__ __align__(16) u16 B3s[128 * 64];
  __shared__ int toks[128];

  const int e = blockIdx.z;
  int cnt = counts[e];
  if ((unsigned)cnt > CAP) cnt = 0;
  const int m0 = blockIdx.y * 128;
  if (m0 >= cnt) return;
  const int n0 = blockIdx.x * 128;
  const int tid = threadIdx.x;

  if (tid < 128) {
    int r = m0 + tid;
    int it = lists[e * CAP + (r < cnt ? r : 0)];
    toks[tid] = ((unsigned)it < NITEM) ? it : 0;
  }
  __syncthreads();

  const int lane = tid & 63;
  const int wr = ((tid >> 7) & 1) * 64;
  const int wc = ((tid >> 6) & 1) * 64;
  const int lr = lane & 15;
  const int kg = lane >> 4;

  const int srow = tid >> 3;                 // staging row 0..31
  const int csw = ((tid & 7) ^ (srow & 7)) * 8;  // pre-swizzled source column

  const u16* xsrc[4];
#pragma unroll
  for (int p = 0; p < 4; ++p)
    xsrc[p] = xb + (size_t)(toks[p * 32 + srow] >> 1) * DIM + csw;  // item -> token
  const u16* b1src = w1b + ((size_t)e * HID + n0 + srow) * DIM + csw;
  const u16* b3src = w3b + ((size_t)e * HID + n0 + srow) * DIM + csw;

  char* aD = (char*)As + tid * 16;
  char* b1D = (char*)B1s + tid * 16;
  char* b3D = (char*)B3s + tid * 16;

  f32x4 acc1[4][4] = {};
  f32x4 acc3[4][4] = {};

  for (int k0 = 0; k0 < DIM; k0 += 64) {
#pragma unroll
    for (int p = 0; p < 4; ++p) {
      async16(xsrc[p] + k0, aD + p * 4096);
      async16(b1src + (size_t)(p * 32) * DIM + k0, b1D + p * 4096);
      async16(b3src + (size_t)(p * 32) * DIM + k0, b3D + p * 4096);
    }
    __syncthreads();
#pragma unroll
    for (int kk = 0; kk < 2; ++kk) {
      const int ko = kk * 32 + kg * 8;
      bf16x8 a[4];
#pragma unroll
      for (int m = 0; m < 4; ++m) a[m] = *fragp(As, wr + m * 16 + lr, ko);
#pragma unroll
      for (int n = 0; n < 4; ++n) {
        bf16x8 b1 = *fragp(B1s, wc + n * 16 + lr, ko);
        bf16x8 b3 = *fragp(B3s, wc + n * 16 + lr, ko);
#pragma unroll
        for (int m = 0; m < 4; ++m) {
          acc1[m][n] = __builtin_amdgcn_mfma_f32_16x16x32_bf16(a[m], b1, acc1[m][n], 0, 0, 0);
          acc3[m][n] = __builtin_amdgcn_mfma_f32_16x16x32_bf16(a[m], b3, acc3[m][n], 0, 0, 0);
        }
      }
    }
    __syncthreads();
  }

#pragma unroll
  for (int m = 0; m < 4; ++m) {
#pragma unroll
    for (int r = 0; r < 4; ++r) {
      const int row = wr + m * 16 + kg * 4 + r;
      if (m0 + row < cnt) {
        const int it = toks[row];
        u16* gp = G + (size_t)it * HID + n0 + wc + lr;
#pragma unroll
        for (int n = 0; n < 4; ++n) {
          float v1 = acc1[m][n][r];
          float v3 = acc3[m][n][r];
          float s = v1 / (1.f + __expf(-v1)) * v3;
          gp[n * 16] = f2bf(s);
        }
      }
    }
  }
}

// GEMM2: out[item][d] = G[item][:] . w2t[e][d][:]  (64x64 tiles for occupancy)
__global__ __launch_bounds__(256) void gemm2A(
    const u16* __restrict__ G, const u16* __restrict__ w2t,
    const int* __restrict__ counts, const int* __restrict__ lists,
    float* __restrict__ out) {
  __shared__ __align__(16) u16 As[64 * 64];
  __shared__ __align__(16) u16 Bs[64 * 64];
  __shared__ int toks[64];

  const int e = blockIdx.z;
  int cnt = counts[e];
  if ((unsigned)cnt > CAP) cnt = 0;
  const int m0 = blockIdx.y * 64;
  if (m0 >= cnt) return;
  const int n0 = blockIdx.x * 64;
  const int tid = threadIdx.x;

  if (tid < 64) {
    int r = m0 + tid;
    int it = lists[e * CAP + (r < cnt ? r : 0)];
    toks[tid] = ((unsigned)it < NITEM) ? it : 0;
  }
  __syncthreads();

  const int lane = tid & 63;
  const int wr = ((tid >> 7) & 1) * 32;
  const int wc = ((tid >> 6) & 1) * 32;
  const int lr = lane & 15;
  const int kg = lane >> 4;

  const int srow = tid >> 3;  // 0..31
  const int csw = ((tid & 7) ^ (srow & 7)) * 8;

  const u16* asrc[2];
#pragma unroll
  for (int p = 0; p < 2; ++p)
    asrc[p] = G + (size_t)toks[p * 32 + srow] * HID + csw;
  const u16* bsrc = w2t + ((size_t)e * DIM + n0 + srow) * HID + csw;

  char* aD = (char*)As + tid * 16;
  char* bD = (char*)Bs + tid * 16;

  f32x4 acc[2][2] = {};

  for (int k0 = 0; k0 < HID; k0 += 64) {
#pragma unroll
    for (int p = 0; p < 2; ++p) {
      async16(asrc[p] + k0, aD + p * 4096);
      async16(bsrc + (size_t)(p * 32) * HID + k0, bD + p * 4096);
    }
    __syncthreads();
#pragma unroll
    for (int kk = 0; kk < 2; ++kk) {
      const int ko = kk * 32 + kg * 8;
      bf16x8 a[2], b[2];
#pragma unroll
      for (int m = 0; m < 2; ++m) a[m] = *fragp(As, wr + m * 16 + lr, ko);
#pragma unroll
      for (int n = 0; n < 2; ++n) b[n] = *fragp(Bs, wc + n * 16 + lr, ko);
#pragma unroll
      for (int n = 0; n < 2; ++n)
#pragma unroll
        for (int m = 0; m < 2; ++m)
          acc[m][n] = __builtin_amdgcn_mfma_f32_16x16x32_bf16(a[m], b[n], acc[m][n], 0, 0, 0);
    }
    __syncthreads();
  }

#pragma unroll
  for (int m = 0; m < 2; ++m) {
#pragma unroll
    for (int r = 0; r < 4; ++r) {
      const int row = wr + m * 16 + kg * 4 + r;
      if (m0 + row < cnt) {
        const int it = toks[row];
        float* op = out + (size_t)it * DIM + n0 + wc + lr;
#pragma unroll
        for (int n = 0; n < 2; ++n)
          op[n * 16] = acc[m][n][r];
      }
    }
  }
}

// ---------------- Path B (fallback, small workspace): round-2 kernels ----------------

__global__ __launch_bounds__(256, 2) void gemm1B(
    const float* __restrict__ x, const float* __restrict__ w1,
    const float* __restrict__ w3, const int* __restrict__ counts,
    const int* __restrict__ lists, u16* __restrict__ G) {
  __shared__ __align__(16) u16 As[128 * LDP];
  __shared__ __align__(16) u16 B1s[128 * LDP];
  __shared__ __align__(16) u16 B3s[128 * LDP];
  __shared__ int toks[128];

  const int e = blockIdx.z;
  int cnt = counts[e];
  if ((unsigned)cnt > CAP) cnt = 0;
  const int m0 = blockIdx.y * 128;
  if (m0 >= cnt) return;
  const int n0 = blockIdx.x * 128;
  const int tid = threadIdx.x;

  if (tid < 128) {
    int r = m0 + tid;
    int it = lists[e * CAP + (r < cnt ? r : 0)];
    toks[tid] = ((unsigned)it < NITEM) ? it : 0;
  }
  __syncthreads();

  const int lane = tid & 63;
  const int wr = ((tid >> 7) & 1) * 64;
  const int wc = ((tid >> 6) & 1) * 64;
  const int lr = lane & 15;
  const int kg = lane >> 4;
  const int arow = tid >> 3;
  const int c8 = (tid & 7) * 8;

  const float* xsrc[4];
#pragma unroll
  for (int p = 0; p < 4; ++p)
    xsrc[p] = x + (size_t)(toks[p * 32 + arow] >> 1) * DIM + c8;
  const float* w1p = w1 + ((size_t)e * HID + n0 + arow) * DIM + c8;
  const float* w3p = w3 + ((size_t)e * HID + n0 + arow) * DIM + c8;

  f32x4 acc1[4][4] = {};
  f32x4 acc3[4][4] = {};

  for (int k0 = 0; k0 < DIM; k0 += 64) {
#pragma unroll
    for (int p = 0; p < 4; ++p) {
      float4 v0 = *(const float4*)(xsrc[p] + k0);
      float4 v1 = *(const float4*)(xsrc[p] + k0 + 4);
      uint4 u;
      u.x = pk2(v0.x, v0.y); u.y = pk2(v0.z, v0.w);
      u.z = pk2(v1.x, v1.y); u.w = pk2(v1.z, v1.w);
      *(uint4*)&As[(p * 32 + arow) * LDP + c8] = u;
    }
#pragma unroll
    for (int p = 0; p < 4; ++p) {
      float4 v0 = *(const float4*)(w1p + (size_t)(p * 32) * DIM + k0);
      float4 v1 = *(const float4*)(w1p + (size_t)(p * 32) * DIM + k0 + 4);
      uint4 u;
      u.x = pk2(v0.x, v0.y); u.y = pk2(v0.z, v0.w);
      u.z = pk2(v1.x, v1.y); u.w = pk2(v1.z, v1.w);
      *(uint4*)&B1s[(p * 32 + arow) * LDP + c8] = u;
      v0 = *(const float4*)(w3p + (size_t)(p * 32) * DIM + k0);
      v1 = *(const float4*)(w3p + (size_t)(p * 32) * DIM + k0 + 4);
      u.x = pk2(v0.x, v0.y); u.y = pk2(v0.z, v0.w);
      u.z = pk2(v1.x, v1.y); u.w = pk2(v1.z, v1.w);
      *(uint4*)&B3s[(p * 32 + arow) * LDP + c8] = u;
    }
    __syncthreads();
#pragma unroll
    for (int kk = 0; kk < 2; ++kk) {
      const int ko = kk * 32 + kg * 8;
      bf16x8 a[4];
#pragma unroll
      for (int m = 0; m < 4; ++m)
        a[m] = *(const bf16x8*)&As[(wr + m * 16 + lr) * LDP + ko];
#pragma unroll
      for (int n = 0; n < 4; ++n) {
        bf16x8 b1 = *(const bf16x8*)&B1s[(wc + n * 16 + lr) * LDP + ko];
        bf16x8 b3 = *(const bf16x8*)&B3s[(wc + n * 16 + lr) * LDP + ko];
#pragma unroll
        for (int m = 0; m < 4; ++m) {
          acc1[m][n] = __builtin_amdgcn_mfma_f32_16x16x32_bf16(a[m], b1, acc1[m][n], 0, 0, 0);
          acc3[m][n] = __builtin_amdgcn_mfma_f32_16x16x32_bf16(a[m], b3, acc3[m][n], 0, 0, 0);
        }
      }
    }
    __syncthreads();
  }

#pragma unroll
  for (int m = 0; m < 4; ++m) {
#pragma unroll
    for (int r = 0; r < 4; ++r) {
      const int row = wr + m * 16 + kg * 4 + r;
      if (m0 + row < cnt) {
        const int it = toks[row];
        u16* gp = G + (size_t)it * HID + n0 + wc + lr;
#pragma unroll
        for (int n = 0; n < 4; ++n) {
          float v1 = acc1[m][n][r];
          float v3 = acc3[m][n][r];
          float s = v1 / (1.f + __expf(-v1)) * v3;
          gp[n * 16] = f2bf(s);
        }
      }
    }
  }
}

__global__ __launch_bounds__(256, 2) void gemm2B(
    const u16* __restrict__ G, const float* __restrict__ w2,
    const int* __restrict__ counts, const int* __restrict__ lists,
    float* __restrict__ out) {
  __shared__ __align__(16) u16 As[128 * LDP];
  __shared__ __align__(16) u16 Bs[128 * LDP];
  __shared__ int toks[128];

  const int e = blockIdx.z;
  int cnt = counts[e];
  if ((unsigned)cnt > CAP) cnt = 0;
  const int m0 = blockIdx.y * 128;
  if (m0 >= cnt) return;
  const int n0 = blockIdx.x * 128;
  const int tid = threadIdx.x;

  if (tid < 128) {
    int r = m0 + tid;
    int it = lists[e * CAP + (r < cnt ? r : 0)];
    toks[tid] = ((unsigned)it < NITEM) ? it : 0;
  }
  __syncthreads();

  const int lane = tid & 63;
  const int wr = ((tid >> 7) & 1) * 64;
  const int wc = ((tid >> 6) & 1) * 64;
  const int lr = lane & 15;
  const int kg = lane >> 4;
  const int arow = tid >> 3;
  const int c8 = (tid & 7) * 8;
  const int brow = tid >> 5;
  const int d4 = (tid & 31) * 4;

  const u16* asrc[4];
#pragma unroll
  for (int p = 0; p < 4; ++p)
    asrc[p] = G + (size_t)toks[p * 32 + arow] * HID + c8;
  const float* bsrc = w2 + ((size_t)e * HID) * DIM + n0 + d4;

  f32x4 acc[4][4] = {};

  for (int k0 = 0; k0 < HID; k0 += 64) {
#pragma unroll
    for (int p = 0; p < 4; ++p) {
      uint4 u = *(const uint4*)(asrc[p] + k0);
      *(uint4*)&As[(p * 32 + arow) * LDP + c8] = u;
    }
#pragma unroll
    for (int p = 0; p < 8; ++p) {
      const int hl = p * 8 + brow;
      float4 v = *(const float4*)(bsrc + (size_t)(k0 + hl) * DIM);
      Bs[(d4 + 0) * LDP + hl] = f2bf(v.x);
      Bs[(d4 + 1) * LDP + hl] = f2bf(v.y);
      Bs[(d4 + 2) * LDP + hl] = f2bf(v.z);
      Bs[(d4 + 3) * LDP + hl] = f2bf(v.w);
    }
    __syncthreads();
#pragma unroll
    for (int kk = 0; kk < 2; ++kk) {
      const int ko = kk * 32 + kg * 8;
      bf16x8 a[4];
#pragma unroll
      for (int m = 0; m < 4; ++m)
        a[m] = *(const bf16x8*)&As[(wr + m * 16 + lr) * LDP + ko];
#pragma unroll
      for (int n = 0; n < 4; ++n) {
        bf16x8 b = *(const bf16x8*)&Bs[(wc + n * 16 + lr) * LDP + ko];
#pragma unroll
        for (int m = 0; m < 4; ++m)
          acc[m][n] = __builtin_amdgcn_mfma_f32_16x16x32_bf16(a[m], b, acc[m][n], 0, 0, 0);
      }
    }
    __syncthreads();
  }

#pragma unroll
  for (int m = 0; m < 4; ++m) {
#pragma unroll
    for (int r = 0; r < 4; ++r) {
      const int row = wr + m * 16 + kg * 4 + r;
      if (m0 + row < cnt) {
        const int it = toks[row];
        float* op = out + (size_t)it * DIM + n0 + wc + lr;
#pragma unroll
        for (int n = 0; n < 4; ++n)
          op[n * 16] = acc[m][n][r];
      }
    }
  }
}

extern "C" void kernel_launch(void* const* d_in, const int* in_sizes, int n_in,
                              void* d_out, int out_size, void* d_ws, size_t ws_size,
                              hipStream_t stream) {
  (void)in_sizes; (void)n_in; (void)out_size;
  const float* x  = (const float*)d_in[0];
  const int*   ei = (const int*)d_in[1];
  const float* w1 = (const float*)d_in[2];
  const float* w2 = (const float*)d_in[3];
  const float* w3 = (const float*)d_in[4];
  float* out = (float*)d_out;

  char* ws = (char*)d_ws;

  // Path A layout: G | xb | w1b | w3b | w2t | counts | lists
  const size_t oG = 0;
  const size_t oXB = 23068672u;
  const size_t oW1 = oXB + 4194304u;
  const size_t oW3 = oW1 + 46137344u;
  const size_t oW2T = oW3 + 46137344u;
  const size_t oCNT = oW2T + 46137344u;
  const size_t oLST = oCNT + 64u;
  const size_t needA = oLST + 131072u;  // ~165.8 MB

  if (ws_size >= needA) {
    u16* G      = (u16*)(ws + oG);
    u16* xb     = (u16*)(ws + oXB);
    u16* w1b    = (u16*)(ws + oW1);
    u16* w3b    = (u16*)(ws + oW3);
    u16* w2t    = (u16*)(ws + oW2T);
    int* counts = (int*)(ws + oCNT);
    int* lists  = (int*)(ws + oLST);

    zero8<<<1, 64, 0, stream>>>(counts);
    bucket<<<NITEM / 256, 256, 0, stream>>>(ei, counts, lists);
    cvt8<<<(NTOK * DIM / 8) / 256, 256, 0, stream>>>(x, xb, NTOK * DIM / 8);
    cvt8<<<(NEXP * HID * DIM / 8) / 256, 256, 0, stream>>>(w1, w1b, NEXP * HID * DIM / 8);
    cvt8<<<(NEXP * HID * DIM / 8) / 256, 256, 0, stream>>>(w3, w3b, NEXP * HID * DIM / 8);
    tw2<<<dim3(DIM / 64, HID / 64, NEXP), 256, 0, stream>>>(w2, w2t);
    gemm1A<<<dim3(HID / 128, CAP / 128, NEXP), 256, 0, stream>>>(xb, w1b, w3b, counts, lists, G);
    gemm2A<<<dim3(DIM / 64, CAP / 64, NEXP), 256, 0, stream>>>(G, w2t, counts, lists, out);
  } else {
    // fallback: compact workspace, on-the-fly conversion (round-2 path)
    u16* G      = (u16*)ws;
    int* counts = (int*)(ws + 23068672u);
    int* lists  = (int*)(ws + 23068736u);

    zero8<<<1, 64, 0, stream>>>(counts);
    bucket<<<NITEM / 256, 256, 0, stream>>>(ei, counts, lists);
    gemm1B<<<dim3(HID / 128, CAP / 128, NEXP), 256, 0, stream>>>(x, w1, w3, counts, lists, G);
    gemm2B<<<dim3(DIM / 128, CAP / 128, NEXP), 256, 0, stream>>>(G, w2, counts, lists, out);
  }
}